// Round 12
// baseline (50.292 us; speedup 1.0000x reference)
//
#include <hip/hip_runtime.h>

// Fused RoI max-pool: stage ROI rectangles original-layout -> LDS (on-the-fly
// transpose), pool channel-last from LDS. ONE kernel, no workspace.
// features [4,256,38,38] f32, rois [512,5] f32, out [512,256,7,7] f32.
//
// Block = (cg 0..3, roi 0..511), 256 threads = 4 waves.
// Stage: chunk = 2 feature rows x 64 ch; thread (sc=tid>>2, syi, sxh) copies
//        half a row via aligned float2; LDS stride 77/channel (odd -> banks
//        spread, 2 lanes/bank = free). Double-buffered: next chunk's global
//        loads issue before current chunk's consume (regs, static idx).
// Pool:  wave wv owns p-rows {wv, wv+4}; lane = channel; compile-time
//        bins<WW> fmax tree via switch(ww); acc in VGPRs.
// Out:   acc -> LDS (aliased) -> coalesced flat stores (verified R5 code).

#define NROIS 512
#define CCH   256
#define FH    38
#define FW    38
#define HW    (FH * FW)          // 1444
#define SCALE 0.0625f
#define NEGF  (-3.402823466e+38f)
#define CSTR  77                 // LDS floats per channel (2*38+1, odd)

template <int WW>
__device__ __forceinline__ void bins(const float (&v)[WW], float (&acc)[7])
{
    #pragma unroll
    for (int q = 0; q < 7; ++q) {
        const int xs = (q * WW) / 7;
        const int xe = ((q + 1) * WW + 6) / 7;
        #pragma unroll
        for (int j = xs; j < xe; ++j)
            acc[q] = fmaxf(acc[q], v[j]);
    }
}

template <int WW>
__device__ __forceinline__ void consume_chunk(
    const float* __restrict__ cb,       // &buf[lane*CSTR + x1]
    bool gA0, bool gA1, bool gB0, bool gB1,
    float (&accA)[7], float (&accB)[7])
{
    if (gA0 | gB0) {
        float v[WW];
        #pragma unroll
        for (int j = 0; j < WW; ++j) v[j] = cb[j];
        if (gA0) bins<WW>(v, accA);
        if (gB0) bins<WW>(v, accB);
    }
    if (gA1 | gB1) {
        float v[WW];
        #pragma unroll
        for (int j = 0; j < WW; ++j) v[j] = cb[FW + j];
        if (gA1) bins<WW>(v, accA);
        if (gB1) bins<WW>(v, accB);
    }
}

#define CONSUME_DISPATCH(WWV)                                                  \
    switch (WWV) {                                                             \
        case  1: consume_chunk< 1>(cb, gA0, gA1, gB0, gB1, accA, accB); break; \
        case  2: consume_chunk< 2>(cb, gA0, gA1, gB0, gB1, accA, accB); break; \
        case  3: consume_chunk< 3>(cb, gA0, gA1, gB0, gB1, accA, accB); break; \
        case  4: consume_chunk< 4>(cb, gA0, gA1, gB0, gB1, accA, accB); break; \
        case  5: consume_chunk< 5>(cb, gA0, gA1, gB0, gB1, accA, accB); break; \
        case  6: consume_chunk< 6>(cb, gA0, gA1, gB0, gB1, accA, accB); break; \
        case  7: consume_chunk< 7>(cb, gA0, gA1, gB0, gB1, accA, accB); break; \
        case  8: consume_chunk< 8>(cb, gA0, gA1, gB0, gB1, accA, accB); break; \
        case  9: consume_chunk< 9>(cb, gA0, gA1, gB0, gB1, accA, accB); break; \
        case 10: consume_chunk<10>(cb, gA0, gA1, gB0, gB1, accA, accB); break; \
        case 11: consume_chunk<11>(cb, gA0, gA1, gB0, gB1, accA, accB); break; \
        case 12: consume_chunk<12>(cb, gA0, gA1, gB0, gB1, accA, accB); break; \
        case 13: consume_chunk<13>(cb, gA0, gA1, gB0, gB1, accA, accB); break; \
        case 14: consume_chunk<14>(cb, gA0, gA1, gB0, gB1, accA, accB); break; \
        case 15: consume_chunk<15>(cb, gA0, gA1, gB0, gB1, accA, accB); break; \
        case 16: consume_chunk<16>(cb, gA0, gA1, gB0, gB1, accA, accB); break; \
        case 17: consume_chunk<17>(cb, gA0, gA1, gB0, gB1, accA, accB); break; \
        case 18: consume_chunk<18>(cb, gA0, gA1, gB0, gB1, accA, accB); break; \
        case 19: consume_chunk<19>(cb, gA0, gA1, gB0, gB1, accA, accB); break; \
        case 20: consume_chunk<20>(cb, gA0, gA1, gB0, gB1, accA, accB); break; \
        case 21: consume_chunk<21>(cb, gA0, gA1, gB0, gB1, accA, accB); break; \
        case 22: consume_chunk<22>(cb, gA0, gA1, gB0, gB1, accA, accB); break; \
        case 23: consume_chunk<23>(cb, gA0, gA1, gB0, gB1, accA, accB); break; \
        case 24: consume_chunk<24>(cb, gA0, gA1, gB0, gB1, accA, accB); break; \
        case 25: consume_chunk<25>(cb, gA0, gA1, gB0, gB1, accA, accB); break; \
        case 26: consume_chunk<26>(cb, gA0, gA1, gB0, gB1, accA, accB); break; \
        case 27: consume_chunk<27>(cb, gA0, gA1, gB0, gB1, accA, accB); break; \
        case 28: consume_chunk<28>(cb, gA0, gA1, gB0, gB1, accA, accB); break; \
        case 29: consume_chunk<29>(cb, gA0, gA1, gB0, gB1, accA, accB); break; \
        case 30: consume_chunk<30>(cb, gA0, gA1, gB0, gB1, accA, accB); break; \
        case 31: consume_chunk<31>(cb, gA0, gA1, gB0, gB1, accA, accB); break; \
        case 32: consume_chunk<32>(cb, gA0, gA1, gB0, gB1, accA, accB); break; \
        case 33: consume_chunk<33>(cb, gA0, gA1, gB0, gB1, accA, accB); break; \
        case 34: consume_chunk<34>(cb, gA0, gA1, gB0, gB1, accA, accB); break; \
        case 35: consume_chunk<35>(cb, gA0, gA1, gB0, gB1, accA, accB); break; \
        case 36: consume_chunk<36>(cb, gA0, gA1, gB0, gB1, accA, accB); break; \
        case 37: consume_chunk<37>(cb, gA0, gA1, gB0, gB1, accA, accB); break; \
        default: consume_chunk<38>(cb, gA0, gA1, gB0, gB1, accA, accB); break; \
    }

__global__ __launch_bounds__(256) void roipool_fused(
    const float* __restrict__ feat,
    const float* __restrict__ rois,
    float* __restrict__ out)
{
    __shared__ float shmem[2][64 * CSTR];   // 2 x 19712 B, double-buffered

    const int n    = blockIdx.y;            // ROI
    const int cg   = blockIdx.x;            // channel group 0..3
    const int tid  = threadIdx.x;
    const int wv   = __builtin_amdgcn_readfirstlane(tid >> 6);
    const int lane = tid & 63;              // channel (consume)
    const int sc   = tid >> 2;              // channel (stage)
    const int syi  = (tid >> 1) & 1;        // staged row parity
    const int sxh  = tid & 1;               // x-half

    // ---- ROI decode (block-uniform) ----
    const float* rr = rois + n * 5;
    const int b = (int)rr[0];
    int x1 = (int)(rr[1] * SCALE);
    int y1 = (int)(rr[2] * SCALE);
    int x2 = (int)(rr[3] * SCALE);
    int y2 = (int)(rr[4] * SCALE);
    x1 = min(max(x1, 0), FW - 1);
    y1 = min(max(y1, 0), FH - 1);
    x2 = min(max(x2, 0), FW - 1);
    y2 = min(max(y2, 0), FH - 1);
    const int hh = y2 - y1 + 1;
    const int ww = x2 - x1 + 1;

    // ---- p-rows owned by this wave ----
    const int pA  = wv;
    const int pB  = wv + 4;                 // 7 => inactive
    const int ysA = y1 + (pA * hh) / 7;
    const int yeA = y1 + ((pA + 1) * hh + 6) / 7;
    const int ysB = y1 + (pB * hh) / 7;
    const int yeB = (pB < 7) ? (y1 + ((pB + 1) * hh + 6) / 7) : -1;

    float accA[7], accB[7];
    #pragma unroll
    for (int q = 0; q < 7; ++q) { accA[q] = NEGF; accB[q] = NEGF; }

    // ---- staging geometry (float2-aligned x range) ----
    const int j2lo  = x1 >> 1;
    const int j2hi  = x2 >> 1;              // <= 18
    const int jbase = j2lo + sxh;
    const float* gch = feat + ((size_t)(b * CCH + cg * 64 + sc)) * HW;

    const int nch = (hh + 1) >> 1;          // chunks of 2 rows

    // ---- prologue: stage chunk 0 into shmem[0] ----
    {
        const int y = y1 + syi;
        if (y <= y2) {
            const float* grow = gch + y * FW;
            float* lrow = &shmem[0][sc * CSTR + syi * FW];
            #pragma unroll
            for (int k = 0; k < 10; ++k) {
                const int j2 = jbase + 2 * k;
                if (j2 <= j2hi) {
                    const float2 v = *(const float2*)(grow + 2 * j2);
                    lrow[2 * j2]     = v.x;
                    lrow[2 * j2 + 1] = v.y;
                }
            }
        }
    }
    __syncthreads();

    // ---- main loop: overlap stage(c+1) with consume(c) ----
    #pragma unroll 1
    for (int c = 0; c < nch; ++c) {
        const int ych = c * 2;

        // issue next chunk's global loads into regs (static indices)
        float2 tmp[10];
        const int yn = y1 + ych + 2 + syi;
        const bool yok = (c + 1 < nch) && (yn <= y2);
        if (yok) {
            const float* grow = gch + yn * FW;
            #pragma unroll
            for (int k = 0; k < 10; ++k) {
                const int j2 = jbase + 2 * k;
                if (j2 <= j2hi) tmp[k] = *(const float2*)(grow + 2 * j2);
            }
        }

        // consume current chunk from LDS
        const int ya = y1 + ych, yb = ya + 1;
        const bool gA0 = (ya >= ysA) & (ya < yeA);
        const bool gA1 = (yb <= y2) & (yb >= ysA) & (yb < yeA);
        const bool gB0 = (pB < 7) & (ya >= ysB) & (ya < yeB);
        const bool gB1 = (pB < 7) & (yb <= y2) & (yb >= ysB) & (yb < yeB);
        const float* cb = &shmem[c & 1][lane * CSTR + x1];
        if (gA0 | gA1 | gB0 | gB1) {
            CONSUME_DISPATCH(ww)
        }

        // write next chunk into the other buffer
        if (yok) {
            float* lrow = &shmem[(c + 1) & 1][sc * CSTR + syi * FW];
            #pragma unroll
            for (int k = 0; k < 10; ++k) {
                const int j2 = jbase + 2 * k;
                if (j2 <= j2hi) { lrow[2 * j2] = tmp[k].x; lrow[2 * j2 + 1] = tmp[k].y; }
            }
        }
        __syncthreads();
    }

    // ---- results -> LDS (aliased over buffers) -> coalesced stores ----
    float (*sm)[65] = (float (*)[65]) &shmem[0][0];   // 49*65 floats < 64*CSTR
    #pragma unroll
    for (int q = 0; q < 7; ++q) sm[pA * 7 + q][lane] = accA[q];
    if (pB < 7) {
        #pragma unroll
        for (int q = 0; q < 7; ++q) sm[pB * 7 + q][lane] = accB[q];
    }
    __syncthreads();

    float* outb = out + (size_t)n * (CCH * 49) + cg * (64 * 49);
    int flat = tid;
    int cc   = tid / 49;
    int pq   = tid - cc * 49;
    #pragma unroll
    for (int k = 0; k < 13; ++k) {
        if (flat < 3136)
            outb[cc * 49 + pq] = sm[pq][cc];
        flat += 256;
        cc += 5; pq += 11;              // 256 = 5*49 + 11
        if (pq >= 49) { pq -= 49; cc += 1; }
    }
}

extern "C" void kernel_launch(void* const* d_in, const int* in_sizes, int n_in,
                              void* d_out, int out_size, void* d_ws, size_t ws_size,
                              hipStream_t stream) {
    const float* feat = (const float*)d_in[0];
    const float* rois = (const float*)d_in[1];
    float* out = (float*)d_out;

    dim3 grid(4, NROIS);                // 4 channel groups x 512 ROIs
    roipool_fused<<<grid, 256, 0, stream>>>(feat, rois, out);
}

// Round 14
// 35.455 us; speedup vs baseline: 1.4185x; 1.4185x over previous
//
#include <hip/hip_runtime.h>

// RoI max-pool via channel-last transpose; float2 channel-paired pooling
// + non-temporal output stores. Two kernels (coop launch fails in harness).
// features [4,256,38,38] f32, rois [512,5] f32, out [512,256,7,7] f32.
// ws: featT [4][1444][256] f32

#define NROIS 512
#define CCH   256
#define FH    38
#define FW    38
#define HW    (FH * FW)          // 1444
#define SCALE 0.0625f
#define NEGF  (-3.402823466e+38f)

#define FEATT_BYTES ((size_t)4 * HW * CCH * sizeof(float))   // 5,914,624

__device__ __forceinline__ void roi_decode(
    const float* __restrict__ rr,
    int& bb, int& x1, int& y1, int& x2, int& y2, int& hh, int& ww)
{
    bb = (int)rr[0];
    x1 = (int)(rr[1] * SCALE);
    y1 = (int)(rr[2] * SCALE);
    x2 = (int)(rr[3] * SCALE);
    y2 = (int)(rr[4] * SCALE);
    x1 = min(max(x1, 0), FW - 1);
    y1 = min(max(y1, 0), FH - 1);
    x2 = min(max(x2, 0), FW - 1);
    y2 = min(max(y2, 0), FH - 1);
    hh = y2 - y1 + 1;
    ww = x2 - x1 + 1;
}

// ---------------- Kernel 1: transpose [4][256][1444] -> [4][1444][256] ----
__global__ __launch_bounds__(256) void transpose_kernel(
    const float* __restrict__ src, float* __restrict__ dst)
{
    __shared__ float tile[4][257];
    const int b  = blockIdx.y;
    const int s0 = blockIdx.x * 4;
    const int t  = threadIdx.x;                 // = channel

    const float4 v = *(const float4*)(src + ((size_t)(b * CCH + t)) * HW + s0);
    tile[0][t] = v.x; tile[1][t] = v.y; tile[2][t] = v.z; tile[3][t] = v.w;
    __syncthreads();

    const int s = t >> 6;                       // 0..3
    const int m = t & 63;
    float* drow = dst + ((size_t)b * HW + s0 + s) * CCH;
    #pragma unroll
    for (int k = 0; k < 4; ++k)
        drow[m + 64 * k] = tile[s][m + 64 * k];
}

// ---------------- Kernel 2: pooling, float2 channel pairs ----------------
template <int WW>
__device__ __forceinline__ void pool_one(
    const float* __restrict__ rb, int h, float2 (&acc)[7])
{
    for (int y = 0; y < h; ++y) {
        float2 v[WW];
        #pragma unroll
        for (int j = 0; j < WW; ++j)
            v[j] = *(const float2*)(rb + j * CCH);
        #pragma unroll
        for (int q = 0; q < 7; ++q) {
            const int xs = (q * WW) / 7;
            const int xe = ((q + 1) * WW + 6) / 7;
            #pragma unroll
            for (int j = xs; j < xe; ++j) {
                acc[q].x = fmaxf(acc[q].x, v[j].x);
                acc[q].y = fmaxf(acc[q].y, v[j].y);
            }
        }
        rb += (size_t)FW * CCH;
    }
}

__global__ __launch_bounds__(256) void roipool_kernel(
    const float* __restrict__ featT,
    const float* __restrict__ rois,
    float* __restrict__ out)
{
    __shared__ float smem[49][130];            // [pq][128 ch], 2-way banks = free

    const int n    = blockIdx.y;               // ROI
    const int cg2  = blockIdx.x;               // 128-ch group: 0 or 1
    const int tid  = threadIdx.x;
    const int wv   = __builtin_amdgcn_readfirstlane(tid >> 6);
    const int lane = tid & 63;                 // -> channels 2*lane, 2*lane+1

    int bb, x1, y1, x2, y2, hh, ww;
    roi_decode(rois + n * 5, bb, x1, y1, x2, y2, hh, ww);

    const float* fb = featT + (size_t)bb * HW * CCH + cg2 * 128 + 2 * lane
                    + (size_t)x1 * CCH;

    // wave wv handles p-rows {wv, wv+4}
    for (int p = wv; p < 7; p += 4) {
        const int ys = y1 + (p * hh) / 7;
        const int h  = (y1 + ((p + 1) * hh + 6) / 7) - ys;

        const float* rb0 = fb + (size_t)(ys * FW) * CCH;

        float2 acc[7];
        #pragma unroll
        for (int q = 0; q < 7; ++q) { acc[q].x = NEGF; acc[q].y = NEGF; }

        switch (ww) {
            case  1: pool_one< 1>(rb0, h, acc); break;
            case  2: pool_one< 2>(rb0, h, acc); break;
            case  3: pool_one< 3>(rb0, h, acc); break;
            case  4: pool_one< 4>(rb0, h, acc); break;
            case  5: pool_one< 5>(rb0, h, acc); break;
            case  6: pool_one< 6>(rb0, h, acc); break;
            case  7: pool_one< 7>(rb0, h, acc); break;
            case  8: pool_one< 8>(rb0, h, acc); break;
            case  9: pool_one< 9>(rb0, h, acc); break;
            case 10: pool_one<10>(rb0, h, acc); break;
            case 11: pool_one<11>(rb0, h, acc); break;
            case 12: pool_one<12>(rb0, h, acc); break;
            case 13: pool_one<13>(rb0, h, acc); break;
            case 14: pool_one<14>(rb0, h, acc); break;
            case 15: pool_one<15>(rb0, h, acc); break;
            case 16: pool_one<16>(rb0, h, acc); break;
            case 17: pool_one<17>(rb0, h, acc); break;
            case 18: pool_one<18>(rb0, h, acc); break;
            case 19: pool_one<19>(rb0, h, acc); break;
            case 20: pool_one<20>(rb0, h, acc); break;
            case 21: pool_one<21>(rb0, h, acc); break;
            case 22: pool_one<22>(rb0, h, acc); break;
            case 23: pool_one<23>(rb0, h, acc); break;
            case 24: pool_one<24>(rb0, h, acc); break;
            case 25: pool_one<25>(rb0, h, acc); break;
            case 26: pool_one<26>(rb0, h, acc); break;
            case 27: pool_one<27>(rb0, h, acc); break;
            case 28: pool_one<28>(rb0, h, acc); break;
            case 29: pool_one<29>(rb0, h, acc); break;
            case 30: pool_one<30>(rb0, h, acc); break;
            case 31: pool_one<31>(rb0, h, acc); break;
            case 32: pool_one<32>(rb0, h, acc); break;
            case 33: pool_one<33>(rb0, h, acc); break;
            case 34: pool_one<34>(rb0, h, acc); break;
            case 35: pool_one<35>(rb0, h, acc); break;
            case 36: pool_one<36>(rb0, h, acc); break;
            case 37: pool_one<37>(rb0, h, acc); break;
            default: pool_one<38>(rb0, h, acc); break;
        }

        #pragma unroll
        for (int q = 0; q < 7; ++q) {
            smem[p * 7 + q][2 * lane]     = acc[q].x;
            smem[p * 7 + q][2 * lane + 1] = acc[q].y;
        }
    }
    __syncthreads();

    // coalesced flat NT stores: 128 ch * 49 bins = 6272 outputs per block
    float* outb = out + (size_t)n * (CCH * 49) + cg2 * (128 * 49);
    #pragma unroll
    for (int k = 0; k < 25; ++k) {
        const int f = k * 256 + tid;
        if (f < 6272) {
            const int c  = f / 49;             // compile-time magic div
            const int pq = f - c * 49;
            __builtin_nontemporal_store(smem[pq][c], &outb[f]);
        }
    }
}

// ---------------- Fallback (ws too small) ----------------
__global__ __launch_bounds__(256) void roipool_fallback(
    const float* __restrict__ feat,
    const float* __restrict__ rois,
    float* __restrict__ out)
{
    int idx = blockIdx.x * blockDim.x + threadIdx.x;
    int q = idx % 7;
    int t = idx / 7;
    int p = t % 7;
    t /= 7;
    int c = t % CCH;
    int n = t / CCH;

    int bb, x1, y1, x2, y2, hh, ww;
    roi_decode(rois + n * 5, bb, x1, y1, x2, y2, hh, ww);

    int ys = y1 + (p * hh) / 7, ye = y1 + ((p + 1) * hh + 6) / 7;
    int xs = x1 + (q * ww) / 7, xe = x1 + ((q + 1) * ww + 6) / 7;

    const float* base = feat + ((size_t)bb * CCH + c) * HW;
    float m = NEGF;
    for (int y = ys; y < ye; ++y)
        for (int x = xs; x < xe; ++x)
            m = fmaxf(m, base[y * FW + x]);
    out[idx] = m;
}

extern "C" void kernel_launch(void* const* d_in, const int* in_sizes, int n_in,
                              void* d_out, int out_size, void* d_ws, size_t ws_size,
                              hipStream_t stream) {
    const float* feat = (const float*)d_in[0];
    const float* rois = (const float*)d_in[1];
    float* out = (float*)d_out;

    if (ws_size < FEATT_BYTES) {
        const int total = NROIS * CCH * 49;
        roipool_fallback<<<(total + 255) / 256, 256, 0, stream>>>(feat, rois, out);
        return;
    }

    float* featT = (float*)d_ws;

    dim3 tg(HW / 4, 4);                      // (361, 4)
    transpose_kernel<<<tg, 256, 0, stream>>>(feat, featT);

    dim3 pg(2, NROIS);                       // 2 x 128-ch groups x 512 ROIs
    roipool_kernel<<<pg, 256, 0, stream>>>(featT, rois, out);
}